// Round 1
// baseline (521.935 us; speedup 1.0000x reference)
//
#include <hip/hip_runtime.h>

#define NBOX 8192
#define SORT_THREADS 1024

// ---------------------------------------------------------------- prep ------
__global__ void prep_kernel(const float4* __restrict__ boxes,
                            const float* __restrict__ scores,
                            const int* __restrict__ ph, const int* __restrict__ pw,
                            unsigned long long* __restrict__ keys,
                            float4* __restrict__ xyxy, float4* __restrict__ cxcywh,
                            int* __restrict__ counter) {
#pragma clang fp contract(off)
    int i = blockIdx.x * blockDim.x + threadIdx.x;
    if (i == 0) *counter = 0;
    if (i >= NBOX) return;
    float xmax = (float)(*pw - 1);
    float ymax = (float)(*ph - 1);
    float4 b = boxes[i];                    // cx, cy, w, h
    float hw = 0.5f * b.z;
    float hh = 0.5f * b.w;
    float x1 = fminf(fmaxf(b.x - hw, 0.0f), xmax);
    float x2 = fminf(fmaxf(b.x + hw, 0.0f), xmax);
    float y1 = fminf(fmaxf(b.y - hh, 0.0f), ymax);
    float y2 = fminf(fmaxf(b.y + hh, 0.0f), ymax);
    float cw = x2 - x1, chh = y2 - y1;
    bool valid = (cw > 0.0f) && (chh > 0.0f);
    xyxy[i]   = make_float4(x1, y1, x2, y2);
    cxcywh[i] = make_float4(0.5f * (x1 + x2), 0.5f * (y1 + y2), cw, chh);
    // sort key: descending by score among valid (sigmoid is monotone), ties by
    // ascending original index (= stable argsort); invalid (-inf prob) last.
    float s = scores[i];
    unsigned int sb  = __float_as_uint(s);
    unsigned int asc = (sb & 0x80000000u) ? ~sb : (sb | 0x80000000u);
    unsigned int hi  = valid ? ~asc : 0xFFFFFFFFu;   // finite score never maps to 0xFFFFFFFF
    keys[i] = ((unsigned long long)hi << 32) | (unsigned int)i;
}

// ---------------------------------------------------------------- sort ------
__global__ __launch_bounds__(SORT_THREADS)
void sort_kernel(const unsigned long long* __restrict__ keys,
                 const float4* __restrict__ xyxy, const float4* __restrict__ cxcywh,
                 float4* __restrict__ xyxy_s, float4* __restrict__ cxcywh_s,
                 unsigned int* __restrict__ keep) {
    __shared__ unsigned long long sk[NBOX];          // 64 KiB
    int t = threadIdx.x;
    for (int i = t; i < NBOX; i += SORT_THREADS) sk[i] = keys[i];
    __syncthreads();
    for (int k = 2; k <= NBOX; k <<= 1) {
        for (int j = k >> 1; j > 0; j >>= 1) {
            for (int i = t; i < NBOX; i += SORT_THREADS) {
                int p = i ^ j;
                if (p > i) {
                    bool up = ((i & k) == 0);
                    unsigned long long a = sk[i], b = sk[p];
                    if ((a > b) == up) { sk[i] = b; sk[p] = a; }
                }
            }
            __syncthreads();
        }
    }
    for (int i = t; i < NBOX; i += SORT_THREADS) {
        unsigned long long kk = sk[i];
        unsigned int idx = (unsigned int)(kk & 0xFFFFFFFFull);
        unsigned int hi  = (unsigned int)(kk >> 32);
        xyxy_s[i]   = xyxy[idx];
        cxcywh_s[i] = cxcywh[idx];
        keep[i] = (hi != 0xFFFFFFFFu) ? 1u : 0u;     // valid flag
    }
}

// --------------------------------------------------------------- edges ------
// block = 256 threads = 64 rows x 4 j-lanes; stages 256 boxes per LDS tile.
__global__ __launch_bounds__(256)
void edge_kernel(const float4* __restrict__ xyxy_s,
                 unsigned int* __restrict__ edges, int* __restrict__ counter,
                 int ecap) {
#pragma clang fp contract(off)
    __shared__ float4 tile[256];
    int t = threadIdx.x;
    int base = blockIdx.x * 64;
    int i = base + (t >> 2);
    float4 bi = xyxy_s[i];
    float ai = (bi.z - bi.x) * (bi.w - bi.y);
    for (int j0 = 0; j0 <= base + 62; j0 += 256) {
        int jl = j0 + t;
        tile[t] = xyxy_s[jl < NBOX ? jl : NBOX - 1];
        __syncthreads();
        for (int jj = (t & 3); jj < 256; jj += 4) {
            int j = j0 + jj;
            if (j >= i) break;
            float4 bj = tile[jj];
            float aj  = (bj.z - bj.x) * (bj.w - bj.y);
            float ix1 = fmaxf(bi.x, bj.x);
            float iy1 = fmaxf(bi.y, bj.y);
            float ix2 = fminf(bi.z, bj.z);
            float iy2 = fminf(bi.w, bj.w);
            float iw  = fmaxf(ix2 - ix1, 0.0f);
            float ih  = fmaxf(iy2 - iy1, 0.0f);
            float inter = iw * ih;
            float uni   = ai + aj - inter;
            float iou   = inter / fmaxf(uni, 1e-8f);
            if (iou > 0.7f) {
                int pos = atomicAdd(counter, 1);
                if (pos < ecap) edges[pos] = ((unsigned int)i << 16) | (unsigned int)j;
            }
        }
        __syncthreads();
    }
}

// ------------------------------------------------------- resolve + out ------
// Greedy NMS keep[i] = valid[i] && !any(keep[j] for edge (i,j), j<i) is the
// unique fixpoint of a well-founded recursion (DAG, j<i): parallel sweeps
// converge in (dependency depth)+1 iterations. Then prefix-scan keep and
// scatter the first npro kept cxcywh rows (rest zero) == reference top_k.
__global__ __launch_bounds__(SORT_THREADS)
void resolve_out_kernel(const unsigned int* __restrict__ keepg,
                        const unsigned int* __restrict__ edges,
                        const int* __restrict__ counter,
                        const float4* __restrict__ cxcywh_s,
                        float4* __restrict__ out, int npro, int ecap) {
    __shared__ unsigned char kept[NBOX];
    __shared__ unsigned char validb[NBOX];
    __shared__ unsigned char sup[NBOX];
    __shared__ int s_changed;
    __shared__ int wavesum[SORT_THREADS / 64];
    int t = threadIdx.x;
    int E = *counter;
    if (E > ecap) E = ecap;
    for (int i = t; i < NBOX; i += SORT_THREADS) {
        unsigned char v = (unsigned char)keepg[i];
        validb[i] = v;
        kept[i] = v;
    }
    __syncthreads();
    for (int iter = 0; iter < NBOX; ++iter) {
        for (int i = t; i < NBOX; i += SORT_THREADS) sup[i] = 0;
        if (t == 0) s_changed = 0;
        __syncthreads();
        for (int e = t; e < E; e += SORT_THREADS) {
            unsigned int ed = edges[e];
            int i = (int)(ed >> 16), j = (int)(ed & 0xFFFFu);
            if (kept[j]) sup[i] = 1;
        }
        __syncthreads();
        int changed = 0;
        for (int i = t; i < NBOX; i += SORT_THREADS) {
            unsigned char nk = (unsigned char)(validb[i] && !sup[i]);
            if (nk != kept[i]) { kept[i] = nk; changed = 1; }
        }
        if (changed) s_changed = 1;
        __syncthreads();
        int done = (s_changed == 0);
        __syncthreads();
        if (done) break;
    }
    // zero output
    for (int k = t; k < npro; k += SORT_THREADS) out[k] = make_float4(0.f, 0.f, 0.f, 0.f);
    // prefix scan over kept (8 contiguous elems per thread)
    int cbase = t * (NBOX / SORT_THREADS);
    int myc = 0;
#pragma unroll
    for (int r = 0; r < NBOX / SORT_THREADS; ++r) myc += kept[cbase + r];
    int lane = t & 63, wid = t >> 6;
    int v = myc;
    for (int d = 1; d < 64; d <<= 1) {
        int o = __shfl_up(v, d);
        if (lane >= d) v += o;
    }
    if (lane == 63) wavesum[wid] = v;
    __syncthreads();
    if (t == 0) {
        int acc = 0;
        for (int w = 0; w < SORT_THREADS / 64; ++w) { int s = wavesum[w]; wavesum[w] = acc; acc += s; }
    }
    __syncthreads();
    int pos = (v - myc) + wavesum[wid];
#pragma unroll
    for (int r = 0; r < NBOX / SORT_THREADS; ++r) {
        int i = cbase + r;
        if (kept[i]) {
            if (pos < npro) out[pos] = cxcywh_s[i];
            ++pos;
        }
    }
}

// --------------------------------------------------------------- host -------
extern "C" void kernel_launch(void* const* d_in, const int* in_sizes, int n_in,
                              void* d_out, int out_size, void* d_ws, size_t ws_size,
                              hipStream_t stream) {
    const float4* boxes  = (const float4*)d_in[0];
    const float* scores  = (const float*)d_in[1];
    const int* ph        = (const int*)d_in[2];
    const int* pw        = (const int*)d_in[3];

    char* ws = (char*)d_ws;
    size_t off = 0;
    unsigned long long* keys = (unsigned long long*)(ws + off); off += (size_t)NBOX * 8;
    float4* xyxy     = (float4*)(ws + off); off += (size_t)NBOX * 16;
    float4* cxcywh   = (float4*)(ws + off); off += (size_t)NBOX * 16;
    float4* xyxy_s   = (float4*)(ws + off); off += (size_t)NBOX * 16;
    float4* cxcywh_s = (float4*)(ws + off); off += (size_t)NBOX * 16;
    unsigned int* keep = (unsigned int*)(ws + off); off += (size_t)NBOX * 4;
    int* counter = (int*)(ws + off); off += 64;
    unsigned int* edges = (unsigned int*)(ws + off);

    int ecap = 262144;
    if (ws_size > off) {
        size_t room = (ws_size - off) / 4;
        if ((size_t)ecap > room) ecap = (int)room;
    } else {
        ecap = 0;
    }
    int npro = out_size / 4;

    prep_kernel<<<NBOX / 256, 256, 0, stream>>>(boxes, scores, ph, pw, keys, xyxy, cxcywh, counter);
    sort_kernel<<<1, SORT_THREADS, 0, stream>>>(keys, xyxy, cxcywh, xyxy_s, cxcywh_s, keep);
    edge_kernel<<<NBOX / 64, 256, 0, stream>>>(xyxy_s, edges, counter, ecap);
    resolve_out_kernel<<<1, SORT_THREADS, 0, stream>>>(keep, edges, counter, cxcywh_s,
                                                       (float4*)d_out, npro, ecap);
}

// Round 2
// 85.536 us; speedup vs baseline: 6.1019x; 6.1019x over previous
//
#include <hip/hip_runtime.h>

#define NBOX 8192

// ---------------------------------------------------------------- prep ------
__global__ void prep_kernel(const float4* __restrict__ boxes,
                            const float* __restrict__ scores,
                            const int* __restrict__ ph, const int* __restrict__ pw,
                            unsigned long long* __restrict__ keys,
                            float4* __restrict__ xyxy, float4* __restrict__ cxcywh,
                            int* __restrict__ counter) {
#pragma clang fp contract(off)
    int i = blockIdx.x * blockDim.x + threadIdx.x;
    if (i == 0) *counter = 0;
    if (i >= NBOX) return;
    float xmax = (float)(*pw - 1);
    float ymax = (float)(*ph - 1);
    float4 b = boxes[i];                    // cx, cy, w, h
    float hw = 0.5f * b.z;
    float hh = 0.5f * b.w;
    float x1 = fminf(fmaxf(b.x - hw, 0.0f), xmax);
    float x2 = fminf(fmaxf(b.x + hw, 0.0f), xmax);
    float y1 = fminf(fmaxf(b.y - hh, 0.0f), ymax);
    float y2 = fminf(fmaxf(b.y + hh, 0.0f), ymax);
    float cw = x2 - x1, chh = y2 - y1;
    bool valid = (cw > 0.0f) && (chh > 0.0f);
    xyxy[i]   = make_float4(x1, y1, x2, y2);
    cxcywh[i] = make_float4(0.5f * (x1 + x2), 0.5f * (y1 + y2), cw, chh);
    // sort key: descending by score among valid (sigmoid monotone), ties by
    // ascending original index (= stable argsort); invalid (-inf prob) last.
    float s = scores[i];
    unsigned int sb  = __float_as_uint(s);
    unsigned int asc = (sb & 0x80000000u) ? ~sb : (sb | 0x80000000u);
    unsigned int hi  = valid ? ~asc : 0xFFFFFFFFu;
    keys[i] = ((unsigned long long)hi << 32) | (unsigned int)i;
}

// ------------------------------------------------- sort: hybrid bitonic -----
// Phase 1: each block fully sorts a 2048-elem chunk (covers k=2..2048).
__global__ __launch_bounds__(1024)
void sort_local_full(unsigned long long* __restrict__ keys) {
    __shared__ unsigned long long sk[2048];            // 16 KiB
    int t = threadIdx.x;
    int base = blockIdx.x * 2048;
    sk[t]        = keys[base + t];
    sk[t + 1024] = keys[base + t + 1024];
    __syncthreads();
    for (int k = 2; k <= 2048; k <<= 1) {
        for (int j = k >> 1; j > 0; j >>= 1) {
            int i = ((t & ~(j - 1)) << 1) | (t & (j - 1));
            int p = i | j;
            bool up = (((base + i) & k) == 0);
            unsigned long long a = sk[i], b = sk[p];
            if ((a > b) == up) { sk[i] = b; sk[p] = a; }
            __syncthreads();
        }
    }
    keys[base + t]        = sk[t];
    keys[base + t + 1024] = sk[t + 1024];
}

// Global compare-exchange pass (j >= 2048 crosses chunks).
__global__ void sort_global_pass(unsigned long long* __restrict__ keys, int k, int j) {
    int t = blockIdx.x * blockDim.x + threadIdx.x;     // NBOX/2 threads
    int i = ((t & ~(j - 1)) << 1) | (t & (j - 1));
    int p = i | j;
    bool up = ((i & k) == 0);
    unsigned long long a = keys[i], b = keys[p];
    if ((a > b) == up) { keys[i] = b; keys[p] = a; }
}

// Local tail of a merge phase: j = 1024..1 within each 2048-chunk.
__global__ __launch_bounds__(1024)
void sort_local_tail(unsigned long long* __restrict__ keys, int k) {
    __shared__ unsigned long long sk[2048];
    int t = threadIdx.x;
    int base = blockIdx.x * 2048;
    sk[t]        = keys[base + t];
    sk[t + 1024] = keys[base + t + 1024];
    __syncthreads();
    bool up = ((base & k) == 0);                       // uniform per chunk (k > 2048)
    for (int j = 1024; j > 0; j >>= 1) {
        int i = ((t & ~(j - 1)) << 1) | (t & (j - 1));
        int p = i | j;
        unsigned long long a = sk[i], b = sk[p];
        if ((a > b) == up) { sk[i] = b; sk[p] = a; }
        __syncthreads();
    }
    keys[base + t]        = sk[t];
    keys[base + t + 1024] = sk[t + 1024];
}

// Gather sorted boxes + valid flags.
__global__ void gather_kernel(const unsigned long long* __restrict__ keys,
                              const float4* __restrict__ xyxy, const float4* __restrict__ cxcywh,
                              float4* __restrict__ xyxy_s, float4* __restrict__ cxcywh_s,
                              unsigned int* __restrict__ keep) {
    int i = blockIdx.x * blockDim.x + threadIdx.x;
    if (i >= NBOX) return;
    unsigned long long kk = keys[i];
    unsigned int idx = (unsigned int)(kk & 0xFFFFFFFFull);
    unsigned int hi  = (unsigned int)(kk >> 32);
    xyxy_s[i]   = xyxy[idx];
    cxcywh_s[i] = cxcywh[idx];
    keep[i] = (hi != 0xFFFFFFFFu) ? 1u : 0u;
}

// --------------------------------------------------------------- edges ------
// Lower-triangular 128x128 tiles; 256 threads = 128 rows x 2 j-lanes.
__global__ __launch_bounds__(256)
void edge_kernel(const float4* __restrict__ xyxy_s,
                 unsigned int* __restrict__ edges, int* __restrict__ counter,
                 int ecap) {
#pragma clang fp contract(off)
    __shared__ float4 tj[128];
    __shared__ float  ta[128];
    int b = blockIdx.x;
    int bi = (int)((sqrtf(8.0f * (float)b + 1.0f) - 1.0f) * 0.5f);
    while ((bi + 1) * (bi + 2) / 2 <= b) ++bi;
    while (bi * (bi + 1) / 2 > b) --bi;
    int bj = b - bi * (bi + 1) / 2;
    int t = threadIdx.x;
    int ib = bi * 128, jb = bj * 128;
    if (t < 128) {
        float4 v = xyxy_s[jb + t];
        tj[t] = v;
        ta[t] = (v.z - v.x) * (v.w - v.y);
    }
    __syncthreads();
    int r = t >> 1, l = t & 1;
    int i = ib + r;
    float4 b4 = xyxy_s[i];
    float ai = (b4.z - b4.x) * (b4.w - b4.y);
    for (int jj = l; jj < 128; jj += 2) {
        int j = jb + jj;
        if (j >= i) break;                 // jj increasing -> ok
        float4 bj4 = tj[jj];
        float ix1 = fmaxf(b4.x, bj4.x);
        float iy1 = fmaxf(b4.y, bj4.y);
        float ix2 = fminf(b4.z, bj4.z);
        float iy2 = fminf(b4.w, bj4.w);
        float iw  = fmaxf(ix2 - ix1, 0.0f);
        float ih  = fmaxf(iy2 - iy1, 0.0f);
        float inter = iw * ih;
        float uni   = ai + ta[jj] - inter;
        float iou   = inter / fmaxf(uni, 1e-8f);
        if (iou > 0.7f) {
            int pos = atomicAdd(counter, 1);
            if (pos < ecap) edges[pos] = ((unsigned int)i << 16) | (unsigned int)j;
        }
    }
}

// ------------------------------------------------------- resolve + out ------
__global__ __launch_bounds__(1024)
void resolve_out_kernel(const unsigned int* __restrict__ keepg,
                        const unsigned int* __restrict__ edges,
                        const int* __restrict__ counter,
                        const float4* __restrict__ cxcywh_s,
                        float4* __restrict__ out, int npro, int ecap) {
    __shared__ unsigned char kept[NBOX];
    __shared__ unsigned char validb[NBOX];
    __shared__ unsigned char sup[NBOX];
    __shared__ int s_changed;
    __shared__ int wavesum[1024 / 64];
    int t = threadIdx.x;
    int E = *counter;
    if (E > ecap) E = ecap;
    for (int i = t; i < NBOX; i += 1024) {
        unsigned char v = (unsigned char)keepg[i];
        validb[i] = v;
        kept[i] = v;
    }
    __syncthreads();
    for (int iter = 0; iter < NBOX; ++iter) {
        for (int i = t; i < NBOX; i += 1024) sup[i] = 0;
        if (t == 0) s_changed = 0;
        __syncthreads();
        for (int e = t; e < E; e += 1024) {
            unsigned int ed = edges[e];
            int i = (int)(ed >> 16), j = (int)(ed & 0xFFFFu);
            if (kept[j]) sup[i] = 1;
        }
        __syncthreads();
        int changed = 0;
        for (int i = t; i < NBOX; i += 1024) {
            unsigned char nk = (unsigned char)(validb[i] && !sup[i]);
            if (nk != kept[i]) { kept[i] = nk; changed = 1; }
        }
        if (changed) s_changed = 1;
        __syncthreads();
        int done = (s_changed == 0);
        __syncthreads();
        if (done) break;
    }
    for (int k = t; k < npro; k += 1024) out[k] = make_float4(0.f, 0.f, 0.f, 0.f);
    int cbase = t * (NBOX / 1024);
    int myc = 0;
#pragma unroll
    for (int r = 0; r < NBOX / 1024; ++r) myc += kept[cbase + r];
    int lane = t & 63, wid = t >> 6;
    int v = myc;
    for (int d = 1; d < 64; d <<= 1) {
        int o = __shfl_up(v, d);
        if (lane >= d) v += o;
    }
    if (lane == 63) wavesum[wid] = v;
    __syncthreads();
    if (t == 0) {
        int acc = 0;
        for (int w = 0; w < 1024 / 64; ++w) { int s = wavesum[w]; wavesum[w] = acc; acc += s; }
    }
    __syncthreads();
    int pos = (v - myc) + wavesum[wid];
#pragma unroll
    for (int r = 0; r < NBOX / 1024; ++r) {
        int i = cbase + r;
        if (kept[i]) {
            if (pos < npro) out[pos] = cxcywh_s[i];
            ++pos;
        }
    }
}

// --------------------------------------------------------------- host -------
extern "C" void kernel_launch(void* const* d_in, const int* in_sizes, int n_in,
                              void* d_out, int out_size, void* d_ws, size_t ws_size,
                              hipStream_t stream) {
    const float4* boxes  = (const float4*)d_in[0];
    const float* scores  = (const float*)d_in[1];
    const int* ph        = (const int*)d_in[2];
    const int* pw        = (const int*)d_in[3];

    char* ws = (char*)d_ws;
    size_t off = 0;
    unsigned long long* keys = (unsigned long long*)(ws + off); off += (size_t)NBOX * 8;
    float4* xyxy     = (float4*)(ws + off); off += (size_t)NBOX * 16;
    float4* cxcywh   = (float4*)(ws + off); off += (size_t)NBOX * 16;
    float4* xyxy_s   = (float4*)(ws + off); off += (size_t)NBOX * 16;
    float4* cxcywh_s = (float4*)(ws + off); off += (size_t)NBOX * 16;
    unsigned int* keep = (unsigned int*)(ws + off); off += (size_t)NBOX * 4;
    int* counter = (int*)(ws + off); off += 64;
    unsigned int* edges = (unsigned int*)(ws + off);

    int ecap = 262144;
    if (ws_size > off) {
        size_t room = (ws_size - off) / 4;
        if ((size_t)ecap > room) ecap = (int)room;
    } else {
        ecap = 0;
    }
    int npro = out_size / 4;

    prep_kernel<<<NBOX / 256, 256, 0, stream>>>(boxes, scores, ph, pw, keys, xyxy, cxcywh, counter);

    // hybrid bitonic sort of 8192 u64 keys
    sort_local_full<<<NBOX / 2048, 1024, 0, stream>>>(keys);
    sort_global_pass<<<NBOX / 2 / 256, 256, 0, stream>>>(keys, 4096, 2048);
    sort_local_tail<<<NBOX / 2048, 1024, 0, stream>>>(keys, 4096);
    sort_global_pass<<<NBOX / 2 / 256, 256, 0, stream>>>(keys, 8192, 4096);
    sort_global_pass<<<NBOX / 2 / 256, 256, 0, stream>>>(keys, 8192, 2048);
    sort_local_tail<<<NBOX / 2048, 1024, 0, stream>>>(keys, 8192);
    gather_kernel<<<NBOX / 256, 256, 0, stream>>>(keys, xyxy, cxcywh, xyxy_s, cxcywh_s, keep);

    int ntiles = NBOX / 128;                                   // 64
    edge_kernel<<<ntiles * (ntiles + 1) / 2, 256, 0, stream>>>(xyxy_s, edges, counter, ecap);
    resolve_out_kernel<<<1, 1024, 0, stream>>>(keep, edges, counter, cxcywh_s,
                                               (float4*)d_out, npro, ecap);
}